// Round 16
// baseline (193.479 us; speedup 1.0000x reference)
//
#include <hip/hip_runtime.h>
#include <hip/hip_fp16.h>
#include <cmath>

static constexpr int NN = 100000;                    // nodes
static constexpr int NE = 2500000;                   // edges
static constexpr int NG = 64;                        // graphs
static constexpr int BSH = 7;                        // bucket shift (128 nodes/bucket)
static constexpr int NBUCK = (NN + 127) / 128;       // 782 buckets of 128 nodes
static constexpr int CSH = 12;                       // staging stride shift (CAP=4096)
static constexpr int CHUNK = 2048;                   // edges per chunk
static constexpr int NCHUNK = (NE + CHUNK - 1) / CHUNK;  // 1221
static constexpr int NSEG = (NCHUNK + 255) / 256;    // 5 scan segments
static constexpr int PQ = NCHUNK / 8;                // chunks per XCD slot
static constexpr int PR = NCHUNK % 8;

union H4 { float2 f2; __half2 h2[2]; };

typedef int   v4i __attribute__((ext_vector_type(4)));
typedef float v2f __attribute__((ext_vector_type(2)));

__device__ inline int4 ntload16(const int4* p) {
    v4i r = __builtin_nontemporal_load((const v4i*)p);
    return make_int4(r.x, r.y, r.z, r.w);
}
__device__ inline float2 ntload8(const float2* p) {
    v2f r = __builtin_nontemporal_load((const v2f*)p);
    return make_float2(r.x, r.y);
}

// ---------- fp8 helpers (gfx950 OCP e4m3 HW converts) ----------
__device__ inline void unpack_add_fp8x16(float* a, const int4 r) {
    auto f = __builtin_amdgcn_cvt_pk_f32_fp8(r.x, false); a[0] += f[0];  a[1] += f[1];
    f = __builtin_amdgcn_cvt_pk_f32_fp8(r.x, true);       a[2] += f[0];  a[3] += f[1];
    f = __builtin_amdgcn_cvt_pk_f32_fp8(r.y, false);      a[4] += f[0];  a[5] += f[1];
    f = __builtin_amdgcn_cvt_pk_f32_fp8(r.y, true);       a[6] += f[0];  a[7] += f[1];
    f = __builtin_amdgcn_cvt_pk_f32_fp8(r.z, false);      a[8] += f[0];  a[9] += f[1];
    f = __builtin_amdgcn_cvt_pk_f32_fp8(r.z, true);       a[10] += f[0]; a[11] += f[1];
    f = __builtin_amdgcn_cvt_pk_f32_fp8(r.w, false);      a[12] += f[0]; a[13] += f[1];
    f = __builtin_amdgcn_cvt_pk_f32_fp8(r.w, true);       a[14] += f[0]; a[15] += f[1];
}

// lane p holds features {2p,2p+1}; merge pairs and have even lanes store one word
__device__ inline void store_fp8_pair(unsigned* row_words, int p, float f0, float f1) {
    unsigned my = ((unsigned)__builtin_amdgcn_cvt_pk_fp8_f32(f0, f1, 0, false)) & 0xFFFFu;
    unsigned nb = (unsigned)__shfl_xor((int)my, 1);
    if ((p & 1) == 0) row_words[p >> 1] = my | (nb << 16);
}

// ---------- P1: per-chunk histogram by dst bucket -> Ht[b][c] ----------
__global__ void p1_hist(const int* __restrict__ dst, int* __restrict__ Ht) {
    __shared__ int hist[NBUCK];
    int t = threadIdx.x, c = blockIdx.x;
    for (int i = t; i < NBUCK; i += 256) hist[i] = 0;
    __syncthreads();
    int e0 = c * CHUNK, e1 = min(e0 + CHUNK, NE);
    for (int e = e0 + t; e < e1; e += 256) atomicAdd(&hist[dst[e] >> BSH], 1);
    __syncthreads();
    for (int b = t; b < NBUCK; b += 256) Ht[(size_t)b * NCHUNK + c] = hist[b];
}

// ---------- P2: per-bucket exclusive scan over chunks (in place) + count; zero pool ----------
__global__ void p2_scan(int* __restrict__ Ht, int* __restrict__ count,
                        float* __restrict__ pooled3) {
    __shared__ int s[256];
    int b = blockIdx.x, t = threadIdx.x;
    if (b == 0 && t < NG * 3) pooled3[t] = 0.0f;
    int* row = Ht + (size_t)b * NCHUNK;
    int carry = 0;
    for (int seg = 0; seg < NSEG; ++seg) {
        int idx = seg * 256 + t;
        int v = (idx < NCHUNK) ? row[idx] : 0;
        __syncthreads();
        s[t] = v;
        __syncthreads();
#pragma unroll
        for (int off = 1; off < 256; off <<= 1) {
            int y = (t >= off) ? s[t - off] : 0;
            __syncthreads();
            s[t] += y;
            __syncthreads();
        }
        int incl = s[t];
        int segtot = s[255];
        if (idx < NCHUNK) row[idx] = incl - v + carry;
        carry += segtot;
    }
    if (t == 0) count[b] = carry;
}

// ---------- P3: deterministic scatter into bucketed staging, XCD-chunked ----------
__global__ void p3_scatter(const int* __restrict__ src, const int* __restrict__ dst,
                           const int* __restrict__ Ht, int* __restrict__ staging) {
    __shared__ int cur[NBUCK];
    int t = threadIdx.x, bid = blockIdx.x;
    int x = bid & 7, o = bid >> 3;
    int len = PQ + (x < PR ? 1 : 0);
    if (o >= len) return;
    int c = x * PQ + min(x, PR) + o;
    for (int b = t; b < NBUCK; b += 256) cur[b] = Ht[(size_t)b * NCHUNK + c];
    __syncthreads();
    int e0 = c * CHUNK, e1 = min(e0 + CHUNK, NE);
    for (int e = e0 + t; e < e1; e += 256) {
        int d = dst[e];
        int b = d >> BSH;
        int r = atomicAdd(&cur[b], 1);
        staging[((size_t)b << CSH) + r] = src[e] | ((d & 127) << 17);
    }
}

// ---------- CSR build per bucket (128 nodes): rsd/dinv/csr_src + fp16 xs ----------
__global__ void csr_build_kernel(const int* __restrict__ staging, const int* __restrict__ count,
                                 const float* __restrict__ x,
                                 unsigned* __restrict__ rsd, float* __restrict__ dinv,
                                 int* __restrict__ csr_src, float2* __restrict__ xsh) {
    __shared__ int hist[256];
    __shared__ int scn[256];
    __shared__ int cur[256];
    int b = blockIdx.x, t = threadIdx.x;
    int cnt = count[b];
    int base = b << CSH;
    hist[t] = 0;
    __syncthreads();
    const int* st = staging + ((size_t)b << CSH);
    for (int i = t; i < cnt; i += 256) atomicAdd(&hist[st[i] >> 17], 1);
    __syncthreads();
    int h = hist[t];
    scn[t] = h; __syncthreads();
#pragma unroll
    for (int off = 1; off < 256; off <<= 1) {
        int y = (t >= off) ? scn[t - off] : 0;
        __syncthreads();
        scn[t] += y;
        __syncthreads();
    }
    int ex = scn[t] - h;
    int v = (b << BSH) + t;
    if (t < 128 && v < NN) {
        float dv = rsqrtf((float)h + 1.0f);  // +1 self-loop
        rsd[v]  = (unsigned)(base + ex) | ((unsigned)h << 23);  // rs: 23 bits, deg: 9 bits
        dinv[v] = dv;
        H4 u;
        u.h2[0] = __floats2half2_rn(x[v * 3] * dv, x[v * 3 + 1] * dv);
        u.h2[1] = __floats2half2_rn(x[v * 3 + 2] * dv, 0.0f);
        xsh[v] = u.f2;
    }
    cur[t] = ex;
    __syncthreads();
    for (int i = t; i < cnt; i += 256) {
        int p = st[i];
        int r = atomicAdd(&cur[p >> 17], 1);
        csr_src[base + r] = p & 0x1FFFF;
    }
}

// ---------- L1: 8 lanes/node, agg width-3 fp16 (unroll-2, nt) + W1+b1+relu+scale -> g2b fp8 ----------
__global__ void __launch_bounds__(256) agg3t1_kernel(const float2* __restrict__ xsh,
        const int* __restrict__ csr, const unsigned* __restrict__ rsd,
        const float* __restrict__ dinv, const float* __restrict__ W1,
        const float* __restrict__ b1, unsigned* __restrict__ g2b) {
    __shared__ float sW1[48], sb1[16];
    int t = threadIdx.x;
    if (t < 48) sW1[t] = W1[t];
    if (t < 16) sb1[t] = b1[t];
    __syncthreads();
    int tid = blockIdx.x * 256 + t;
    int v = tid >> 3, p = tid & 7;
    if (v >= NN) return;
    float a0 = 0.0f, a1 = 0.0f, a2 = 0.0f;
    if (p == 0) {
        H4 u; u.f2 = xsh[v];
        float2 f0 = __half22float2(u.h2[0]), f1 = __half22float2(u.h2[1]);
        a0 = f0.x; a1 = f0.y; a2 = f1.x;
    }
    unsigned rd = rsd[v];
    int s0 = rd & 0x7FFFFF, cnt = (int)(rd >> 23);
    int j = p;
    for (; j + 8 < cnt; j += 16) {
        int s1 = csr[s0 + j];
        int s2 = csr[s0 + j + 8];
        H4 u1; u1.f2 = ntload8(xsh + s1);
        H4 u2; u2.f2 = ntload8(xsh + s2);
        float2 f0 = __half22float2(u1.h2[0]), f1 = __half22float2(u1.h2[1]);
        a0 += f0.x; a1 += f0.y; a2 += f1.x;
        f0 = __half22float2(u2.h2[0]); f1 = __half22float2(u2.h2[1]);
        a0 += f0.x; a1 += f0.y; a2 += f1.x;
    }
    if (j < cnt) {
        H4 u; u.f2 = ntload8(xsh + csr[s0 + j]);
        float2 f0 = __half22float2(u.h2[0]), f1 = __half22float2(u.h2[1]);
        a0 += f0.x; a1 += f0.y; a2 += f1.x;
    }
    a0 += __shfl_xor(a0, 1); a1 += __shfl_xor(a1, 1); a2 += __shfl_xor(a2, 1);
    a0 += __shfl_xor(a0, 2); a1 += __shfl_xor(a1, 2); a2 += __shfl_xor(a2, 2);
    a0 += __shfl_xor(a0, 4); a1 += __shfl_xor(a1, 4); a2 += __shfl_xor(a2, 4);
    float dv = dinv[v];
    a0 *= dv; a1 *= dv; a2 *= dv;
    float f[2];
#pragma unroll
    for (int k = 0; k < 2; ++k) {
        int fo = p * 2 + k;
        float g = fmaf(a0, sW1[fo], fmaf(a1, sW1[16 + fo], fmaf(a2, sW1[32 + fo], sb1[fo])));
        f[k] = fmaxf(g, 0.0f) * dv;
    }
    store_fp8_pair(g2b + (size_t)v * 4, p, f[0], f[1]);
}

// ---------- L2+L3a: 8 lanes/node, agg width-16 fp8 (tier-4/2/1, nt) + cooperative MLP ----------
__global__ void __launch_bounds__(256) agg16mid_kernel(const int4* __restrict__ g2b,
        const int* __restrict__ csr, const unsigned* __restrict__ rsd,
        const float* __restrict__ dinv, const float* __restrict__ W2,
        const float* __restrict__ b2, const float* __restrict__ W3,
        unsigned* __restrict__ g3b) {
    __shared__ float sW2[512], sW3t[512], sb2[32];
    int t = threadIdx.x;
    for (int i = t; i < 512; i += 256) {
        sW2[i] = W2[i];
        int fo = i >> 5, fi = i & 31;
        sW3t[i] = W3[fi * 16 + fo];
    }
    if (t < 32) sb2[t] = b2[t];
    __syncthreads();
    int tid = blockIdx.x * 256 + t;
    int v = tid >> 3, p = tid & 7;
    if (v >= NN) return;
    float a[16];
#pragma unroll
    for (int f = 0; f < 16; ++f) a[f] = 0.0f;
    if (p == 0) unpack_add_fp8x16(a, g2b[v]);
    unsigned rd = rsd[v];
    int s0 = rd & 0x7FFFFF, cnt = (int)(rd >> 23);
    int j = p;
    for (; j + 24 < cnt; j += 32) {
        int s1 = csr[s0 + j];
        int s2 = csr[s0 + j + 8];
        int s3 = csr[s0 + j + 16];
        int s4 = csr[s0 + j + 24];
        int4 xa = ntload16(g2b + s1), xb = ntload16(g2b + s2);
        int4 xc = ntload16(g2b + s3), xd = ntload16(g2b + s4);
        unpack_add_fp8x16(a, xa); unpack_add_fp8x16(a, xb);
        unpack_add_fp8x16(a, xc); unpack_add_fp8x16(a, xd);
    }
    for (; j + 8 < cnt; j += 16) {
        int s1 = csr[s0 + j];
        int s2 = csr[s0 + j + 8];
        int4 xa = ntload16(g2b + s1), xb = ntload16(g2b + s2);
        unpack_add_fp8x16(a, xa); unpack_add_fp8x16(a, xb);
    }
    if (j < cnt) {
        int4 xa = ntload16(g2b + csr[s0 + j]);
        unpack_add_fp8x16(a, xa);
    }
#pragma unroll
    for (int f = 0; f < 16; ++f) a[f] += __shfl_xor(a[f], 1);
#pragma unroll
    for (int f = 0; f < 16; ++f) a[f] += __shfl_xor(a[f], 2);
#pragma unroll
    for (int f = 0; f < 16; ++f) a[f] += __shfl_xor(a[f], 4);
    float dv = dinv[v];
#pragma unroll
    for (int f = 0; f < 16; ++f) a[f] *= dv;
    // cooperative MLP: lane p owns h2[4p..4p+4)
    float h2p[4];
#pragma unroll
    for (int k = 0; k < 4; ++k) {
        int fo = p * 4 + k;
        float s = sb2[fo];
#pragma unroll
        for (int fi = 0; fi < 16; ++fi) s = fmaf(a[fi], sW2[fi * 32 + fo], s);
        h2p[k] = fmaxf(s, 0.0f);
    }
    // partial outputs through transposed W3 (lane-varying fi -> banks 4 apart, conflict-free)
    float po[16];
#pragma unroll
    for (int fo = 0; fo < 16; ++fo) {
        const float* wrow = sW3t + fo * 32 + p * 4;
        float s = h2p[0] * wrow[0];
        s = fmaf(h2p[1], wrow[1], s);
        s = fmaf(h2p[2], wrow[2], s);
        s = fmaf(h2p[3], wrow[3], s);
        po[fo] = s;
    }
#pragma unroll
    for (int f = 0; f < 16; ++f) po[f] += __shfl_xor(po[f], 1);
#pragma unroll
    for (int f = 0; f < 16; ++f) po[f] += __shfl_xor(po[f], 2);
#pragma unroll
    for (int f = 0; f < 16; ++f) po[f] += __shfl_xor(po[f], 4);
    store_fp8_pair(g3b + (size_t)v * 4, p, po[p * 2] * dv, po[p * 2 + 1] * dv);
}

// ---------- L3b+L4a: 8 lanes/node, agg width-16 fp8 (tier-4/2/1, nt) + distributed b3/relu/W4 ----------
__global__ void __launch_bounds__(256) agg16t4_kernel(const int4* __restrict__ g3b,
        const int* __restrict__ csr, const unsigned* __restrict__ rsd,
        const float* __restrict__ dinv, const float* __restrict__ b3,
        const float* __restrict__ W4, float2* __restrict__ g4) {
    __shared__ float sb3[16], sW4[32];
    int t = threadIdx.x;
    if (t < 16) sb3[t] = b3[t];
    if (t < 32) sW4[t] = W4[t];
    __syncthreads();
    int tid = blockIdx.x * 256 + t;
    int v = tid >> 3, p = tid & 7;
    if (v >= NN) return;
    float a[16];
#pragma unroll
    for (int f = 0; f < 16; ++f) a[f] = 0.0f;
    if (p == 0) unpack_add_fp8x16(a, g3b[v]);
    unsigned rd = rsd[v];
    int s0 = rd & 0x7FFFFF, cnt = (int)(rd >> 23);
    int j = p;
    for (; j + 24 < cnt; j += 32) {
        int s1 = csr[s0 + j];
        int s2 = csr[s0 + j + 8];
        int s3 = csr[s0 + j + 16];
        int s4 = csr[s0 + j + 24];
        int4 xa = ntload16(g3b + s1), xb = ntload16(g3b + s2);
        int4 xc = ntload16(g3b + s3), xd = ntload16(g3b + s4);
        unpack_add_fp8x16(a, xa); unpack_add_fp8x16(a, xb);
        unpack_add_fp8x16(a, xc); unpack_add_fp8x16(a, xd);
    }
    for (; j + 8 < cnt; j += 16) {
        int s1 = csr[s0 + j];
        int s2 = csr[s0 + j + 8];
        int4 xa = ntload16(g3b + s1), xb = ntload16(g3b + s2);
        unpack_add_fp8x16(a, xa); unpack_add_fp8x16(a, xb);
    }
    if (j < cnt) {
        int4 xa = ntload16(g3b + csr[s0 + j]);
        unpack_add_fp8x16(a, xa);
    }
#pragma unroll
    for (int f = 0; f < 16; ++f) a[f] += __shfl_xor(a[f], 1);
#pragma unroll
    for (int f = 0; f < 16; ++f) a[f] += __shfl_xor(a[f], 2);
#pragma unroll
    for (int f = 0; f < 16; ++f) a[f] += __shfl_xor(a[f], 4);
    float dv = dinv[v];
    int f0 = p * 2, f1 = p * 2 + 1;
    float h3a = fmaxf(fmaf(a[f0], dv, sb3[f0]), 0.0f);
    float h3b = fmaxf(fmaf(a[f1], dv, sb3[f1]), 0.0f);
    float o0 = fmaf(h3a, sW4[f0 * 2 + 0], h3b * sW4[f1 * 2 + 0]);
    float o1 = fmaf(h3a, sW4[f0 * 2 + 1], h3b * sW4[f1 * 2 + 1]);
    o0 += __shfl_xor(o0, 1); o1 += __shfl_xor(o1, 1);
    o0 += __shfl_xor(o0, 2); o1 += __shfl_xor(o1, 2);
    o0 += __shfl_xor(o0, 4); o1 += __shfl_xor(o1, 4);
    if (p == 0) g4[v] = make_float2(o0 * dv, o1 * dv);
}

// ---------- L4b: 8 lanes/node, agg width-2 (unroll-2, nt) + b4 + graph mean-pool ----------
__global__ void __launch_bounds__(256) agg2pool_kernel(const float2* __restrict__ g4,
        const int* __restrict__ csr, const unsigned* __restrict__ rsd,
        const float* __restrict__ dinv, const float* __restrict__ b4,
        const int* __restrict__ batch, float* __restrict__ pooled3) {
    __shared__ float spool[NG * 3];
    int t = threadIdx.x;
    for (int i = t; i < NG * 3; i += 256) spool[i] = 0.0f;
    __syncthreads();
    int tid = blockIdx.x * 256 + t;
    int v = tid >> 3, p = tid & 7;
    if (v < NN) {
        float a0 = 0.0f, a1 = 0.0f;
        if (p == 0) { float2 s = g4[v]; a0 = s.x; a1 = s.y; }
        unsigned rd = rsd[v];
        int s0 = rd & 0x7FFFFF, cnt = (int)(rd >> 23);
        int j = p;
        for (; j + 8 < cnt; j += 16) {
            float2 q1 = ntload8(g4 + csr[s0 + j]);
            float2 q2 = ntload8(g4 + csr[s0 + j + 8]);
            a0 += q1.x + q2.x; a1 += q1.y + q2.y;
        }
        if (j < cnt) {
            float2 q = ntload8(g4 + csr[s0 + j]);
            a0 += q.x; a1 += q.y;
        }
        a0 += __shfl_xor(a0, 1); a1 += __shfl_xor(a1, 1);
        a0 += __shfl_xor(a0, 2); a1 += __shfl_xor(a1, 2);
        a0 += __shfl_xor(a0, 4); a1 += __shfl_xor(a1, 4);
        if (p == 0) {
            float dv = dinv[v];
            float o0 = fmaf(a0, dv, b4[0]);
            float o1 = fmaf(a1, dv, b4[1]);
            int gi = batch[v];
            atomicAdd(&spool[gi * 3 + 0], o0);
            atomicAdd(&spool[gi * 3 + 1], o1);
            atomicAdd(&spool[gi * 3 + 2], 1.0f);
        }
    }
    __syncthreads();
    for (int i = t; i < NG * 3; i += 256)
        if (spool[i] != 0.0f) atomicAdd(&pooled3[i], spool[i]);
}

// ---------- final: mean + log_softmax ----------
__global__ void lsm_kernel(const float* __restrict__ pooled3, float* __restrict__ out) {
    int g = threadIdx.x;
    if (g < NG) {
        float c = fmaxf(pooled3[g * 3 + 2], 1.0f);
        float a = pooled3[g * 3 + 0] / c;
        float b = pooled3[g * 3 + 1] / c;
        float m = fmaxf(a, b);
        float lse = m + logf(expf(a - m) + expf(b - m));
        out[g * 2 + 0] = a - lse;
        out[g * 2 + 1] = b - lse;
    }
}

extern "C" void kernel_launch(void* const* d_in, const int* in_sizes, int n_in,
                              void* d_out, int out_size, void* d_ws, size_t ws_size,
                              hipStream_t stream) {
    (void)in_sizes; (void)n_in; (void)out_size; (void)ws_size;

    const float* x   = (const float*)d_in[0];
    const int*   ei  = (const int*)d_in[1];
    const int*   bat = (const int*)d_in[2];
    const float* W1  = (const float*)d_in[3];
    const float* b1  = (const float*)d_in[4];
    const float* W2  = (const float*)d_in[5];
    const float* b2  = (const float*)d_in[6];
    const float* W3  = (const float*)d_in[7];
    const float* b3  = (const float*)d_in[8];
    const float* W4  = (const float*)d_in[9];
    const float* b4  = (const float*)d_in[10];
    float* out = (float*)d_out;

    const int* src = ei;
    const int* dst = ei + NE;

    // ---- workspace layout (16B-aligned slabs) ----
    char* w = (char*)d_ws;
    int*      Ht      = (int*)w;      w += ((size_t)NBUCK * NCHUNK * 4 + 15) & ~15ull;  // 3.8 MB
    int*      count   = (int*)w;      w += ((size_t)NBUCK * 4 + 15) & ~15ull;
    int*      staging = (int*)w;      w += ((size_t)NBUCK << CSH) * 4;                  // 12.8 MB
    int*      csr_src = (int*)w;      w += ((size_t)NBUCK << CSH) * 4;                  // 12.8 MB
    unsigned* rsd     = (unsigned*)w; w += (size_t)NN * 4;
    float*    dinv    = (float*)w;    w += (size_t)NN * 4;
    float2*   xsh     = (float2*)w;   w += (size_t)NN * 8;                              // 0.8 MB fp16
    unsigned* g2b     = (unsigned*)w; w += (size_t)NN * 16;                             // 1.6 MB fp8
    unsigned* g3b     = (unsigned*)w; w += (size_t)NN * 16;                             // 1.6 MB fp8
    float2*   g4      = (float2*)w;   w += (size_t)NN * 8;                              // 0.8 MB
    float*    pooled3 = (float*)w;    w += NG * 3 * 4;
    // total ~35 MB

    const int gN8 = (NN * 8 + 255) / 256;   // 3125 blocks (8 lanes per node)
    const int gP3 = 8 * (PQ + 1);           // 1224 blocks

    // ---- CSR build: deterministic multisplit (no global atomics, no memsets) ----
    p1_hist<<<NCHUNK, 256, 0, stream>>>(dst, Ht);
    p2_scan<<<NBUCK, 256, 0, stream>>>(Ht, count, pooled3);   // also zeroes pooled3
    p3_scatter<<<gP3, 256, 0, stream>>>(src, dst, Ht, staging);
    csr_build_kernel<<<NBUCK, 256, 0, stream>>>(staging, count, x, rsd, dinv, csr_src, xsh);

    agg3t1_kernel<<<gN8, 256, 0, stream>>>(xsh, csr_src, rsd, dinv, W1, b1, g2b);
    agg16mid_kernel<<<gN8, 256, 0, stream>>>((const int4*)g2b, csr_src, rsd, dinv, W2, b2,
                                             W3, g3b);
    agg16t4_kernel<<<gN8, 256, 0, stream>>>((const int4*)g3b, csr_src, rsd, dinv, b3, W4, g4);
    agg2pool_kernel<<<gN8, 256, 0, stream>>>(g4, csr_src, rsd, dinv, b4, bat, pooled3);

    lsm_kernel<<<1, 64, 0, stream>>>(pooled3, out);
}

// Round 17
// 141.830 us; speedup vs baseline: 1.3642x; 1.3642x over previous
//
#include <hip/hip_runtime.h>
#include <hip/hip_fp16.h>
#include <cmath>

static constexpr int NN = 100000;                    // nodes
static constexpr int NE = 2500000;                   // edges
static constexpr int NG = 64;                        // graphs
static constexpr int BSH = 7;                        // bucket shift (128 nodes/bucket)
static constexpr int NBUCK = (NN + 127) / 128;       // 782 buckets of 128 nodes
static constexpr int CSH = 12;                       // staging stride shift (CAP=4096)
static constexpr int CHUNK = 4096;                   // edges per chunk
static constexpr int NCHUNK = (NE + CHUNK - 1) / CHUNK;  // 611

union H4 { float2 f2; __half2 h2[2]; };

// ---------- fp8 helpers (gfx950 OCP e4m3 HW converts) ----------
__device__ inline void unpack_add_fp8x16(float* a, const int4 r) {
    auto f = __builtin_amdgcn_cvt_pk_f32_fp8(r.x, false); a[0] += f[0];  a[1] += f[1];
    f = __builtin_amdgcn_cvt_pk_f32_fp8(r.x, true);       a[2] += f[0];  a[3] += f[1];
    f = __builtin_amdgcn_cvt_pk_f32_fp8(r.y, false);      a[4] += f[0];  a[5] += f[1];
    f = __builtin_amdgcn_cvt_pk_f32_fp8(r.y, true);       a[6] += f[0];  a[7] += f[1];
    f = __builtin_amdgcn_cvt_pk_f32_fp8(r.z, false);      a[8] += f[0];  a[9] += f[1];
    f = __builtin_amdgcn_cvt_pk_f32_fp8(r.z, true);       a[10] += f[0]; a[11] += f[1];
    f = __builtin_amdgcn_cvt_pk_f32_fp8(r.w, false);      a[12] += f[0]; a[13] += f[1];
    f = __builtin_amdgcn_cvt_pk_f32_fp8(r.w, true);       a[14] += f[0]; a[15] += f[1];
}

// lane p holds features {2p,2p+1}; merge pairs and have even lanes store one word
__device__ inline void store_fp8_pair(unsigned* row_words, int p, float f0, float f1) {
    unsigned my = ((unsigned)__builtin_amdgcn_cvt_pk_fp8_f32(f0, f1, 0, false)) & 0xFFFFu;
    unsigned nb = (unsigned)__shfl_xor((int)my, 1);
    if ((p & 1) == 0) row_words[p >> 1] = my | (nb << 16);
}

// ---------- P1: per-chunk histogram by dst bucket -> Ht[b][c] ----------
__global__ void p1_hist(const int* __restrict__ dst, int* __restrict__ Ht) {
    __shared__ int hist[NBUCK];
    int t = threadIdx.x, c = blockIdx.x;
    for (int i = t; i < NBUCK; i += 256) hist[i] = 0;
    __syncthreads();
    int e0 = c * CHUNK, e1 = min(e0 + CHUNK, NE);
    for (int e = e0 + t; e < e1; e += 256) atomicAdd(&hist[dst[e] >> BSH], 1);
    __syncthreads();
    for (int b = t; b < NBUCK; b += 256) Ht[(size_t)b * NCHUNK + c] = hist[b];
}

// ---------- P2: per-bucket exclusive scan over chunks (in place) + count; zero pool ----------
__global__ void p2_scan(int* __restrict__ Ht, int* __restrict__ count,
                        float* __restrict__ pooled3) {
    __shared__ int s[256];
    int b = blockIdx.x, t = threadIdx.x;
    if (b == 0 && t < NG * 3) pooled3[t] = 0.0f;
    int* row = Ht + (size_t)b * NCHUNK;
    int carry = 0;
    for (int seg = 0; seg < 3; ++seg) {
        int idx = seg * 256 + t;
        int v = (idx < NCHUNK) ? row[idx] : 0;
        __syncthreads();
        s[t] = v;
        __syncthreads();
#pragma unroll
        for (int off = 1; off < 256; off <<= 1) {
            int y = (t >= off) ? s[t - off] : 0;
            __syncthreads();
            s[t] += y;
            __syncthreads();
        }
        int incl = s[t];
        int segtot = s[255];
        if (idx < NCHUNK) row[idx] = incl - v + carry;
        carry += segtot;
    }
    if (t == 0) count[b] = carry;
}

// ---------- P3: deterministic scatter into bucketed staging, XCD-chunked ----------
__global__ void p3_scatter(const int* __restrict__ src, const int* __restrict__ dst,
                           const int* __restrict__ Ht, int* __restrict__ staging) {
    __shared__ int cur[NBUCK];
    int t = threadIdx.x, bid = blockIdx.x;
    int x = bid & 7, o = bid >> 3;
    int len = 76 + (x < 3 ? 1 : 0);
    if (o >= len) return;
    int c = x * 76 + min(x, 3) + o;
    for (int b = t; b < NBUCK; b += 256) cur[b] = Ht[(size_t)b * NCHUNK + c];
    __syncthreads();
    int e0 = c * CHUNK, e1 = min(e0 + CHUNK, NE);
    for (int e = e0 + t; e < e1; e += 256) {
        int d = dst[e];
        int b = d >> BSH;
        int r = atomicAdd(&cur[b], 1);
        staging[((size_t)b << CSH) + r] = src[e] | ((d & 127) << 17);
    }
}

// ---------- CSR build per bucket (128 nodes): rsd/dinv/csr_src + fp16 xs ----------
__global__ void csr_build_kernel(const int* __restrict__ staging, const int* __restrict__ count,
                                 const float* __restrict__ x,
                                 unsigned* __restrict__ rsd, float* __restrict__ dinv,
                                 int* __restrict__ csr_src, float2* __restrict__ xsh) {
    __shared__ int hist[256];
    __shared__ int scn[256];
    __shared__ int cur[256];
    int b = blockIdx.x, t = threadIdx.x;
    int cnt = count[b];
    int base = b << CSH;
    hist[t] = 0;
    __syncthreads();
    const int* st = staging + ((size_t)b << CSH);
    for (int i = t; i < cnt; i += 256) atomicAdd(&hist[st[i] >> 17], 1);
    __syncthreads();
    int h = hist[t];
    scn[t] = h; __syncthreads();
#pragma unroll
    for (int off = 1; off < 256; off <<= 1) {
        int y = (t >= off) ? scn[t - off] : 0;
        __syncthreads();
        scn[t] += y;
        __syncthreads();
    }
    int ex = scn[t] - h;
    int v = (b << BSH) + t;
    if (t < 128 && v < NN) {
        float dv = rsqrtf((float)h + 1.0f);  // +1 self-loop
        rsd[v]  = (unsigned)(base + ex) | ((unsigned)h << 23);  // rs: 23 bits, deg: 9 bits
        dinv[v] = dv;
        H4 u;
        u.h2[0] = __floats2half2_rn(x[v * 3] * dv, x[v * 3 + 1] * dv);
        u.h2[1] = __floats2half2_rn(x[v * 3 + 2] * dv, 0.0f);
        xsh[v] = u.f2;
    }
    cur[t] = ex;
    __syncthreads();
    for (int i = t; i < cnt; i += 256) {
        int p = st[i];
        int r = atomicAdd(&cur[p >> 17], 1);
        csr_src[base + r] = p & 0x1FFFF;
    }
}

// ---------- L1: 8 lanes/node, agg width-3 fp16 (unroll-2) + W1+b1+relu+scale -> g2b fp8 ----------
__global__ void __launch_bounds__(256) agg3t1_kernel(const float2* __restrict__ xsh,
        const int* __restrict__ csr, const unsigned* __restrict__ rsd,
        const float* __restrict__ dinv, const float* __restrict__ W1,
        const float* __restrict__ b1, unsigned* __restrict__ g2b) {
    __shared__ float sW1[48], sb1[16];
    int t = threadIdx.x;
    if (t < 48) sW1[t] = W1[t];
    if (t < 16) sb1[t] = b1[t];
    __syncthreads();
    int tid = blockIdx.x * 256 + t;
    int v = tid >> 3, p = tid & 7;
    if (v >= NN) return;
    float a0 = 0.0f, a1 = 0.0f, a2 = 0.0f;
    if (p == 0) {
        H4 u; u.f2 = xsh[v];
        float2 f0 = __half22float2(u.h2[0]), f1 = __half22float2(u.h2[1]);
        a0 = f0.x; a1 = f0.y; a2 = f1.x;
    }
    unsigned rd = rsd[v];
    int s0 = rd & 0x7FFFFF, cnt = (int)(rd >> 23);
    int j = p;
    for (; j + 8 < cnt; j += 16) {
        int s1 = csr[s0 + j];
        int s2 = csr[s0 + j + 8];
        H4 u1; u1.f2 = xsh[s1];
        H4 u2; u2.f2 = xsh[s2];
        float2 f0 = __half22float2(u1.h2[0]), f1 = __half22float2(u1.h2[1]);
        a0 += f0.x; a1 += f0.y; a2 += f1.x;
        f0 = __half22float2(u2.h2[0]); f1 = __half22float2(u2.h2[1]);
        a0 += f0.x; a1 += f0.y; a2 += f1.x;
    }
    if (j < cnt) {
        H4 u; u.f2 = xsh[csr[s0 + j]];
        float2 f0 = __half22float2(u.h2[0]), f1 = __half22float2(u.h2[1]);
        a0 += f0.x; a1 += f0.y; a2 += f1.x;
    }
    a0 += __shfl_xor(a0, 1); a1 += __shfl_xor(a1, 1); a2 += __shfl_xor(a2, 1);
    a0 += __shfl_xor(a0, 2); a1 += __shfl_xor(a1, 2); a2 += __shfl_xor(a2, 2);
    a0 += __shfl_xor(a0, 4); a1 += __shfl_xor(a1, 4); a2 += __shfl_xor(a2, 4);
    float dv = dinv[v];
    a0 *= dv; a1 *= dv; a2 *= dv;
    float f[2];
#pragma unroll
    for (int k = 0; k < 2; ++k) {
        int fo = p * 2 + k;
        float g = fmaf(a0, sW1[fo], fmaf(a1, sW1[16 + fo], fmaf(a2, sW1[32 + fo], sb1[fo])));
        f[k] = fmaxf(g, 0.0f) * dv;
    }
    store_fp8_pair(g2b + (size_t)v * 4, p, f[0], f[1]);
}

// ---------- L2+L3a: 8 lanes/node, agg width-16 fp8 (tier-4/2/1) + cooperative MLP ----------
__global__ void __launch_bounds__(256) agg16mid_kernel(const int4* __restrict__ g2b,
        const int* __restrict__ csr, const unsigned* __restrict__ rsd,
        const float* __restrict__ dinv, const float* __restrict__ W2,
        const float* __restrict__ b2, const float* __restrict__ W3,
        unsigned* __restrict__ g3b) {
    __shared__ float sW2[512], sW3t[512], sb2[32];
    int t = threadIdx.x;
    for (int i = t; i < 512; i += 256) {
        sW2[i] = W2[i];
        int fo = i >> 5, fi = i & 31;
        sW3t[i] = W3[fi * 16 + fo];
    }
    if (t < 32) sb2[t] = b2[t];
    __syncthreads();
    int tid = blockIdx.x * 256 + t;
    int v = tid >> 3, p = tid & 7;
    if (v >= NN) return;
    float a[16];
#pragma unroll
    for (int f = 0; f < 16; ++f) a[f] = 0.0f;
    if (p == 0) unpack_add_fp8x16(a, g2b[v]);
    unsigned rd = rsd[v];
    int s0 = rd & 0x7FFFFF, cnt = (int)(rd >> 23);
    int j = p;
    for (; j + 24 < cnt; j += 32) {
        int s1 = csr[s0 + j];
        int s2 = csr[s0 + j + 8];
        int s3 = csr[s0 + j + 16];
        int s4 = csr[s0 + j + 24];
        int4 xa = g2b[s1], xb = g2b[s2], xc = g2b[s3], xd = g2b[s4];
        unpack_add_fp8x16(a, xa); unpack_add_fp8x16(a, xb);
        unpack_add_fp8x16(a, xc); unpack_add_fp8x16(a, xd);
    }
    for (; j + 8 < cnt; j += 16) {
        int s1 = csr[s0 + j];
        int s2 = csr[s0 + j + 8];
        int4 xa = g2b[s1], xb = g2b[s2];
        unpack_add_fp8x16(a, xa); unpack_add_fp8x16(a, xb);
    }
    if (j < cnt) {
        int4 xa = g2b[csr[s0 + j]];
        unpack_add_fp8x16(a, xa);
    }
#pragma unroll
    for (int f = 0; f < 16; ++f) a[f] += __shfl_xor(a[f], 1);
#pragma unroll
    for (int f = 0; f < 16; ++f) a[f] += __shfl_xor(a[f], 2);
#pragma unroll
    for (int f = 0; f < 16; ++f) a[f] += __shfl_xor(a[f], 4);
    float dv = dinv[v];
#pragma unroll
    for (int f = 0; f < 16; ++f) a[f] *= dv;
    // cooperative MLP: lane p owns h2[4p..4p+4)
    float h2p[4];
#pragma unroll
    for (int k = 0; k < 4; ++k) {
        int fo = p * 4 + k;
        float s = sb2[fo];
#pragma unroll
        for (int fi = 0; fi < 16; ++fi) s = fmaf(a[fi], sW2[fi * 32 + fo], s);
        h2p[k] = fmaxf(s, 0.0f);
    }
    // partial outputs through transposed W3 (lane-varying fi -> banks 4 apart, conflict-free)
    float po[16];
#pragma unroll
    for (int fo = 0; fo < 16; ++fo) {
        const float* wrow = sW3t + fo * 32 + p * 4;
        float s = h2p[0] * wrow[0];
        s = fmaf(h2p[1], wrow[1], s);
        s = fmaf(h2p[2], wrow[2], s);
        s = fmaf(h2p[3], wrow[3], s);
        po[fo] = s;
    }
#pragma unroll
    for (int f = 0; f < 16; ++f) po[f] += __shfl_xor(po[f], 1);
#pragma unroll
    for (int f = 0; f < 16; ++f) po[f] += __shfl_xor(po[f], 2);
#pragma unroll
    for (int f = 0; f < 16; ++f) po[f] += __shfl_xor(po[f], 4);
    store_fp8_pair(g3b + (size_t)v * 4, p, po[p * 2] * dv, po[p * 2 + 1] * dv);
}

// ---------- L3b+L4a: 8 lanes/node, agg width-16 fp8 (tier-4/2/1) + distributed b3/relu/W4 ----------
__global__ void __launch_bounds__(256) agg16t4_kernel(const int4* __restrict__ g3b,
        const int* __restrict__ csr, const unsigned* __restrict__ rsd,
        const float* __restrict__ dinv, const float* __restrict__ b3,
        const float* __restrict__ W4, float2* __restrict__ g4) {
    __shared__ float sb3[16], sW4[32];
    int t = threadIdx.x;
    if (t < 16) sb3[t] = b3[t];
    if (t < 32) sW4[t] = W4[t];
    __syncthreads();
    int tid = blockIdx.x * 256 + t;
    int v = tid >> 3, p = tid & 7;
    if (v >= NN) return;
    float a[16];
#pragma unroll
    for (int f = 0; f < 16; ++f) a[f] = 0.0f;
    if (p == 0) unpack_add_fp8x16(a, g3b[v]);
    unsigned rd = rsd[v];
    int s0 = rd & 0x7FFFFF, cnt = (int)(rd >> 23);
    int j = p;
    for (; j + 24 < cnt; j += 32) {
        int s1 = csr[s0 + j];
        int s2 = csr[s0 + j + 8];
        int s3 = csr[s0 + j + 16];
        int s4 = csr[s0 + j + 24];
        int4 xa = g3b[s1], xb = g3b[s2], xc = g3b[s3], xd = g3b[s4];
        unpack_add_fp8x16(a, xa); unpack_add_fp8x16(a, xb);
        unpack_add_fp8x16(a, xc); unpack_add_fp8x16(a, xd);
    }
    for (; j + 8 < cnt; j += 16) {
        int s1 = csr[s0 + j];
        int s2 = csr[s0 + j + 8];
        int4 xa = g3b[s1], xb = g3b[s2];
        unpack_add_fp8x16(a, xa); unpack_add_fp8x16(a, xb);
    }
    if (j < cnt) {
        int4 xa = g3b[csr[s0 + j]];
        unpack_add_fp8x16(a, xa);
    }
#pragma unroll
    for (int f = 0; f < 16; ++f) a[f] += __shfl_xor(a[f], 1);
#pragma unroll
    for (int f = 0; f < 16; ++f) a[f] += __shfl_xor(a[f], 2);
#pragma unroll
    for (int f = 0; f < 16; ++f) a[f] += __shfl_xor(a[f], 4);
    float dv = dinv[v];
    int f0 = p * 2, f1 = p * 2 + 1;
    float h3a = fmaxf(fmaf(a[f0], dv, sb3[f0]), 0.0f);
    float h3b = fmaxf(fmaf(a[f1], dv, sb3[f1]), 0.0f);
    float o0 = fmaf(h3a, sW4[f0 * 2 + 0], h3b * sW4[f1 * 2 + 0]);
    float o1 = fmaf(h3a, sW4[f0 * 2 + 1], h3b * sW4[f1 * 2 + 1]);
    o0 += __shfl_xor(o0, 1); o1 += __shfl_xor(o1, 1);
    o0 += __shfl_xor(o0, 2); o1 += __shfl_xor(o1, 2);
    o0 += __shfl_xor(o0, 4); o1 += __shfl_xor(o1, 4);
    if (p == 0) g4[v] = make_float2(o0 * dv, o1 * dv);
}

// ---------- L4b: 8 lanes/node, agg width-2 (unroll-2) + b4 + graph mean-pool ----------
__global__ void __launch_bounds__(256) agg2pool_kernel(const float2* __restrict__ g4,
        const int* __restrict__ csr, const unsigned* __restrict__ rsd,
        const float* __restrict__ dinv, const float* __restrict__ b4,
        const int* __restrict__ batch, float* __restrict__ pooled3) {
    __shared__ float spool[NG * 3];
    int t = threadIdx.x;
    for (int i = t; i < NG * 3; i += 256) spool[i] = 0.0f;
    __syncthreads();
    int tid = blockIdx.x * 256 + t;
    int v = tid >> 3, p = tid & 7;
    if (v < NN) {
        float a0 = 0.0f, a1 = 0.0f;
        if (p == 0) { float2 s = g4[v]; a0 = s.x; a1 = s.y; }
        unsigned rd = rsd[v];
        int s0 = rd & 0x7FFFFF, cnt = (int)(rd >> 23);
        int j = p;
        for (; j + 8 < cnt; j += 16) {
            float2 q1 = g4[csr[s0 + j]];
            float2 q2 = g4[csr[s0 + j + 8]];
            a0 += q1.x + q2.x; a1 += q1.y + q2.y;
        }
        if (j < cnt) {
            float2 q = g4[csr[s0 + j]];
            a0 += q.x; a1 += q.y;
        }
        a0 += __shfl_xor(a0, 1); a1 += __shfl_xor(a1, 1);
        a0 += __shfl_xor(a0, 2); a1 += __shfl_xor(a1, 2);
        a0 += __shfl_xor(a0, 4); a1 += __shfl_xor(a1, 4);
        if (p == 0) {
            float dv = dinv[v];
            float o0 = fmaf(a0, dv, b4[0]);
            float o1 = fmaf(a1, dv, b4[1]);
            int gi = batch[v];
            atomicAdd(&spool[gi * 3 + 0], o0);
            atomicAdd(&spool[gi * 3 + 1], o1);
            atomicAdd(&spool[gi * 3 + 2], 1.0f);
        }
    }
    __syncthreads();
    for (int i = t; i < NG * 3; i += 256)
        if (spool[i] != 0.0f) atomicAdd(&pooled3[i], spool[i]);
}

// ---------- final: mean + log_softmax ----------
__global__ void lsm_kernel(const float* __restrict__ pooled3, float* __restrict__ out) {
    int g = threadIdx.x;
    if (g < NG) {
        float c = fmaxf(pooled3[g * 3 + 2], 1.0f);
        float a = pooled3[g * 3 + 0] / c;
        float b = pooled3[g * 3 + 1] / c;
        float m = fmaxf(a, b);
        float lse = m + logf(expf(a - m) + expf(b - m));
        out[g * 2 + 0] = a - lse;
        out[g * 2 + 1] = b - lse;
    }
}

extern "C" void kernel_launch(void* const* d_in, const int* in_sizes, int n_in,
                              void* d_out, int out_size, void* d_ws, size_t ws_size,
                              hipStream_t stream) {
    (void)in_sizes; (void)n_in; (void)out_size; (void)ws_size;

    const float* x   = (const float*)d_in[0];
    const int*   ei  = (const int*)d_in[1];
    const int*   bat = (const int*)d_in[2];
    const float* W1  = (const float*)d_in[3];
    const float* b1  = (const float*)d_in[4];
    const float* W2  = (const float*)d_in[5];
    const float* b2  = (const float*)d_in[6];
    const float* W3  = (const float*)d_in[7];
    const float* b3  = (const float*)d_in[8];
    const float* W4  = (const float*)d_in[9];
    const float* b4  = (const float*)d_in[10];
    float* out = (float*)d_out;

    const int* src = ei;
    const int* dst = ei + NE;

    // ---- workspace layout (16B-aligned slabs) ----
    char* w = (char*)d_ws;
    int*      Ht      = (int*)w;      w += ((size_t)NBUCK * NCHUNK * 4 + 15) & ~15ull;  // 1.9 MB
    int*      count   = (int*)w;      w += ((size_t)NBUCK * 4 + 15) & ~15ull;
    int*      staging = (int*)w;      w += ((size_t)NBUCK << CSH) * 4;                  // 12.8 MB
    int*      csr_src = (int*)w;      w += ((size_t)NBUCK << CSH) * 4;                  // 12.8 MB
    unsigned* rsd     = (unsigned*)w; w += (size_t)NN * 4;
    float*    dinv    = (float*)w;    w += (size_t)NN * 4;
    float2*   xsh     = (float2*)w;   w += (size_t)NN * 8;                              // 0.8 MB fp16
    unsigned* g2b     = (unsigned*)w; w += (size_t)NN * 16;                             // 1.6 MB fp8
    unsigned* g3b     = (unsigned*)w; w += (size_t)NN * 16;                             // 1.6 MB fp8
    float2*   g4      = (float2*)w;   w += (size_t)NN * 8;                              // 0.8 MB
    float*    pooled3 = (float*)w;    w += NG * 3 * 4;
    // total ~33 MB

    const int gN8 = (NN * 8 + 255) / 256;   // 3125 blocks (8 lanes per node)

    // ---- CSR build: deterministic multisplit (no global atomics, no memsets) ----
    p1_hist<<<NCHUNK, 256, 0, stream>>>(dst, Ht);
    p2_scan<<<NBUCK, 256, 0, stream>>>(Ht, count, pooled3);   // also zeroes pooled3
    p3_scatter<<<616, 256, 0, stream>>>(src, dst, Ht, staging);
    csr_build_kernel<<<NBUCK, 256, 0, stream>>>(staging, count, x, rsd, dinv, csr_src, xsh);

    agg3t1_kernel<<<gN8, 256, 0, stream>>>(xsh, csr_src, rsd, dinv, W1, b1, g2b);
    agg16mid_kernel<<<gN8, 256, 0, stream>>>((const int4*)g2b, csr_src, rsd, dinv, W2, b2,
                                             W3, g3b);
    agg16t4_kernel<<<gN8, 256, 0, stream>>>((const int4*)g3b, csr_src, rsd, dinv, b3, W4, g4);
    agg2pool_kernel<<<gN8, 256, 0, stream>>>(g4, csr_src, rsd, dinv, b4, bat, pooled3);

    lsm_kernel<<<1, 64, 0, stream>>>(pooled3, out);
}